// Round 11
// baseline (226.721 us; speedup 1.0000x reference)
//
#include <hip/hip_runtime.h>
#include <hip/hip_bf16.h>
#include <cstdint>

#define NH 12
#define DH 64
#define TSEQ 4096
#define BATCH 2
#define CDIM 768
#define MROWS (BATCH*TSEQ)

typedef __bf16 bf16x8 __attribute__((ext_vector_type(8)));
typedef bf16x8 bf16x8_a __attribute__((may_alias));
typedef float f32x4 __attribute__((ext_vector_type(4)));
typedef float f32x16 __attribute__((ext_vector_type(16)));
typedef uint32_t u32;

__device__ __forceinline__ uint16_t f2bu(float f) {
  uint32_t u = __float_as_uint(f);
  u += 0x7fffu + ((u >> 16) & 1u);
  return (uint16_t)(u >> 16);
}

__device__ __forceinline__ float bu2f(uint16_t x) {
  return __uint_as_float(((uint32_t)x) << 16);
}

__device__ __forceinline__ u32 pkbf(float a, float b) {
  union { __bf16 h[2]; u32 u; } t;
  t.h[0] = (__bf16)a; t.h[1] = (__bf16)b;
  return t.u;
}

__device__ __forceinline__ bf16x8 mkfrag(u32 a, u32 b, u32 c, u32 d) {
  union { u32 u[4]; bf16x8 v; } t;
  t.u[0] = a; t.u[1] = b; t.u[2] = c; t.u[3] = d;
  return t.v;
}

__device__ __forceinline__ void gload_lds16(const void* g, void* l) {
  __builtin_amdgcn_global_load_lds(
      (const __attribute__((address_space(1))) void*)g,
      (__attribute__((address_space(3))) void*)l, 16, 0, 0);
}

// ---------------- cast fp32 -> bf16 (vectorized) ----------------
__global__ void cast_f32_bf16(const float* __restrict__ in, uint16_t* __restrict__ out, int n4) {
  int i = blockIdx.x * blockDim.x + threadIdx.x;
  int stride = gridDim.x * blockDim.x;
  for (; i < n4; i += stride) {
    float4 v = ((const float4*)in)[i];
    ushort4 o;
    o.x = f2bu(v.x); o.y = f2bu(v.y); o.z = f2bu(v.z); o.w = f2bu(v.w);
    ((ushort4*)out)[i] = o;
  }
}

// ---------------- transpose + cast: W[K][N] f32 -> Wt[N][K] bf16 ----------------
__global__ void transpose_cast(const float* __restrict__ w, uint16_t* __restrict__ wt, int K, int N) {
  __shared__ float tile[32][33];
  int kb = blockIdx.x * 32, nb = blockIdx.y * 32;
  int tx = threadIdx.x & 31, ty = threadIdx.x >> 5;
  #pragma unroll
  for (int r = ty; r < 32; r += 8) tile[r][tx] = w[(size_t)(kb + r) * N + nb + tx];
  __syncthreads();
  #pragma unroll
  for (int r = ty; r < 32; r += 8) wt[(size_t)(nb + r) * K + kb + tx] = f2bu(tile[tx][r]);
}

// ---------------- GEMM: C[M,N] = A[M,K](bf16) @ Bt[N,K]^T(bf16) + bias ----------------
template <int MODE>
__global__ __launch_bounds__(256) void gemm_bt(
    const uint16_t* __restrict__ A, const uint16_t* __restrict__ Bt,
    const float* __restrict__ bias,
    uint16_t* __restrict__ q, uint16_t* __restrict__ k, uint16_t* __restrict__ v,
    float* __restrict__ outf, int N, int K) {
  __shared__ uint16_t As[128 * 32];
  __shared__ uint16_t Bs[128 * 32];
  int tid = threadIdx.x;
  int w = tid >> 6, l = tid & 63;
  int lg = l >> 4, lr = l & 15;
  int mb = blockIdx.x * 128, nb = blockIdx.y * 128;
  int wr = (w >> 1) * 64, wc = (w & 1) * 64;
  f32x4 acc[4][4] = {};
  int srow = tid >> 2, scol = (tid & 3) * 8;
  const uint16_t* Ag = A + (size_t)(mb + srow) * K + scol;
  const uint16_t* Bg = Bt + (size_t)(nb + srow) * K + scol;
  char* AsB = (char*)As + (size_t)w * 1024;
  char* BsB = (char*)Bs + (size_t)w * 1024;
  size_t rowskip = (size_t)64 * K;
  for (int kb = 0; kb < K; kb += 32) {
    __syncthreads();
    gload_lds16(Ag + kb, AsB);
    gload_lds16(Ag + kb + rowskip, AsB + 4096);
    gload_lds16(Bg + kb, BsB);
    gload_lds16(Bg + kb + rowskip, BsB + 4096);
    __syncthreads();
    bf16x8 af[4], bfr[4];
    #pragma unroll
    for (int i = 0; i < 4; ++i)
      af[i] = *(const bf16x8_a*)(const void*)(As + (wr + i * 16 + lr) * 32 + lg * 8);
    #pragma unroll
    for (int i = 0; i < 4; ++i)
      bfr[i] = *(const bf16x8_a*)(const void*)(Bs + (wc + i * 16 + lr) * 32 + lg * 8);
    #pragma unroll
    for (int mi = 0; mi < 4; ++mi)
      #pragma unroll
      for (int ni = 0; ni < 4; ++ni)
        acc[mi][ni] = __builtin_amdgcn_mfma_f32_16x16x32_bf16(af[mi], bfr[ni], acc[mi][ni], 0, 0, 0);
  }
  #pragma unroll
  for (int mi = 0; mi < 4; ++mi) {
    #pragma unroll
    for (int ni = 0; ni < 4; ++ni) {
      if (MODE == 0) {
        int gm0 = mb + wr + mi * 16 + lg * 4;
        int gn = nb + wc + ni * 16 + lr;
        int which = gn / CDIM;
        int cc = gn - which * CDIM;
        int hh = cc >> 6, d = cc & 63;
        float bs = bias[gn];
        if (which == 2) {
          int b0 = gm0 >> 12, t0 = gm0 & 4095;
          ushort4 pk;
          pk.x = f2bu(acc[mi][ni][0] + bs);
          pk.y = f2bu(acc[mi][ni][1] + bs);
          pk.z = f2bu(acc[mi][ni][2] + bs);
          pk.w = f2bu(acc[mi][ni][3] + bs);
          *(ushort4*)&v[(((size_t)(b0 * NH + hh)) * DH + d) * TSEQ + t0] = pk;
        } else {
          uint16_t* dst = which ? k : q;
          float sc = which ? 1.0f : 0.1803368801111204f;  // 0.125 * log2(e)
          #pragma unroll
          for (int j = 0; j < 4; ++j) {
            int gm = gm0 + j;
            int bb = gm >> 12, t = gm & 4095;
            float val = (acc[mi][ni][j] + bs) * sc;
            dst[(((size_t)(bb * NH + hh)) * TSEQ + t) * DH + d] = f2bu(val);
          }
        }
      } else {
        #pragma unroll
        for (int j = 0; j < 4; ++j) {
          int gm = mb + wr + mi * 16 + lg * 4 + j;
          int gn = nb + wc + ni * 16 + lr;
          outf[(size_t)gm * N + gn] = acc[mi][ni][j] + bias[gn];
        }
      }
    }
  }
}

// ---------------- flash attention: 32x32x16 datapath, single-buffer LDS, split-KV --------
// 256 thr / 4 waves; wave w owns 32 q-rows at qb+32w (QBLK=128); KVBLK=64.
// K/V single-buffered in swizzled 16KB LDS (no P tile; P stays in registers).
// Two barriers per tile (r9-proven structure); TLP (~4 resident blocks/CU) hides stage.
// Fixed-reference softmax: p = exp2(S) directly (Q pre-scaled by 0.125*log2e),
// partials over disjoint k-ranges are exactly additive -> split-KV without rescale.
// Swapped QK^T: S = mfma(K_frag, Q_frag); lane owns q-col (l&31);
// k distributed over regs: k = (r&3)+8*(r>>2)+4*(l>>5) per 32-k subtile.
// gid = widx*24 + bh; widx<32: chunk blocks of qt=31..16; widx>=32: direct qt=15..0.
__global__ __launch_bounds__(256) void attn_part(
    const uint16_t* __restrict__ Q, const uint16_t* __restrict__ K,
    const uint16_t* __restrict__ Vt, uint16_t* __restrict__ O,
    uint16_t* __restrict__ Pbuf, float* __restrict__ Plsum) {
  int gid = blockIdx.x;
  int widx = gid / 24, bh = gid - widx * 24;
  int qt, t0, t1, chunk;
  bool direct;
  if (widx < 32) {
    qt = 31 - (widx >> 1); chunk = widx & 1; direct = false;
    t0 = chunk ? (qt + 1) : 0;
    t1 = chunk ? (2 * qt + 1) : qt;
  } else {
    qt = 47 - widx; chunk = 0; direct = true;
    t0 = 0; t1 = 2 * qt + 1;
  }
  int b = bh / NH, hd = bh - b * NH;
  size_t base = (size_t)bh * TSEQ * DH;
  int tid = threadIdx.x, w = tid >> 6, l = tid & 63;
  int h = l >> 5, lrow = l & 31, l7 = lrow & 7;
  __shared__ __align__(16) uint16_t Ks[64 * 64];
  __shared__ __align__(16) uint16_t Vs[64 * 64];
  // staging: pre-swizzled global source, linear LDS dest (16B chunk c of row r at slot c^(r&7))
  int srow = tid >> 3;                  // 0..31
  int schunk = (tid & 7) ^ (srow & 7);
  const uint16_t* Kg0 = K + base + (size_t)srow * DH + schunk * 8;
  const uint16_t* Vg0 = Vt + base + (size_t)srow * TSEQ + schunk * 8;

  int qb = qt * 128;
  int qw = qb + 32 * w;                 // wave's first q row
  int qg = qw + lrow;                   // lane's q row
  bf16x8 qf[4];                         // [dk]: Q[q][16dk + 8h + 0..7]
  #pragma unroll
  for (int dk = 0; dk < 4; ++dk)
    qf[dk] = *(const bf16x8_a*)(Q + base + (size_t)qg * DH + dk * 16 + h * 8);

#define STAGE(tv) do { \
    char* kd_ = (char*)Ks + w * 1024; \
    char* vd_ = (char*)Vs + w * 1024; \
    const uint16_t* kg_ = Kg0 + (size_t)(tv) * (64 * DH); \
    const uint16_t* vg_ = Vg0 + (size_t)(tv) * 64; \
    gload_lds16(kg_,           kd_); \
    gload_lds16(kg_ + 32 * DH, kd_ + 4096); \
    gload_lds16(vg_,                     vd_); \
    gload_lds16(vg_ + (size_t)32 * TSEQ, vd_ + 4096); \
  } while (0)

  f32x16 o0 = {}, o1 = {};              // D cols d = lrow / 32+lrow
  float lsum = 0.f;
  for (int t = t0; t <= t1; ++t) {
    __syncthreads();                    // all waves done reading previous tile
    STAGE(t);
    __syncthreads();                    // stage complete (vmcnt drain)
    const char* Kc = (const char*)Ks;
    const char* Vc = (const char*)Vs;
    #pragma unroll
    for (int tk = 0; tk < 2; ++tk) {
      int k0 = t * 64 + 32 * tk;
      if (k0 <= qw) {                   // wave-uniform causal skip (both mult of 32)
        // ---- QK^T: 4 MFMA ----
        bf16x8 kf[4];
        #pragma unroll
        for (int dk = 0; dk < 4; ++dk)
          kf[dk] = *(const bf16x8_a*)(Kc + (32 * tk + lrow) * 128 + (((2 * dk + h) ^ l7) << 4));
        f32x16 s = {};
        __builtin_amdgcn_s_setprio(1);
        #pragma unroll
        for (int dk = 0; dk < 4; ++dk)
          s = __builtin_amdgcn_mfma_f32_32x32x16_bf16(kf[dk], qf[dk], s, 0, 0, 0);
        __builtin_amdgcn_s_setprio(0);
        // ---- causal mask (diagonal subtile only: k0 == qw) ----
        if (k0 == qw) {
          #pragma unroll
          for (int r = 0; r < 16; ++r) {
            int kl = (r & 3) + 8 * (r >> 2) + 4 * h;
            s[r] = (kl <= lrow) ? s[r] : -1e30f;
          }
        }
        // ---- p = exp2(S), pack bf16 pairs, accumulate l ----
        u32 cc[8];
        #pragma unroll
        for (int g = 0; g < 4; ++g) {
          float a0 = __builtin_amdgcn_exp2f(s[4 * g + 0]);
          float a1 = __builtin_amdgcn_exp2f(s[4 * g + 1]);
          float a2 = __builtin_amdgcn_exp2f(s[4 * g + 2]);
          float a3 = __builtin_amdgcn_exp2f(s[4 * g + 3]);
          lsum += (a0 + a1) + (a2 + a3);
          cc[2 * g] = pkbf(a0, a1);
          cc[2 * g + 1] = pkbf(a2, a3);
        }
        // ---- cross-half exchange for PV A-fragments ----
        u32 x[4];
        #pragma unroll
        for (int j = 0; j < 4; ++j) {
          int jj = (j >> 1) * 4 + (j & 1);        // {0,1,4,5}[j]
          u32 sel = h ? cc[jj] : cc[jj + 2];
          x[j] = (u32)__shfl_xor((int)sel, 32, 64);
        }
        // ---- PV: 4 MFMA ----
        __builtin_amdgcn_s_setprio(1);
        #pragma unroll
        for (int ks = 0; ks < 2; ++ks) {
          int i0 = 4 * ks, j0 = 2 * ks;
          bf16x8 p = h ? mkfrag(x[j0], x[j0 + 1], cc[i0 + 2], cc[i0 + 3])
                       : mkfrag(cc[i0], cc[i0 + 1], x[j0], x[j0 + 1]);
          int vchunk = ((2 * (2 * tk + ks) + h) ^ l7) << 4;
          bf16x8 vf0 = *(const bf16x8_a*)(Vc + lrow * 128 + vchunk);
          bf16x8 vf1 = *(const bf16x8_a*)(Vc + (32 + lrow) * 128 + vchunk);
          o0 = __builtin_amdgcn_mfma_f32_32x32x16_bf16(p, vf0, o0, 0, 0, 0);
          o1 = __builtin_amdgcn_mfma_f32_32x32x16_bf16(p, vf1, o1, 0, 0, 0);
        }
        __builtin_amdgcn_s_setprio(0);
      }
    }
  }
#undef STAGE

  lsum += __shfl_xor(lsum, 32, 64);     // full row sum for q = qw + lrow
  if (direct) {
    float linv = 1.0f / lsum;
    #pragma unroll
    for (int r = 0; r < 16; ++r) {
      int rl = (r & 3) + 8 * (r >> 2) + 4 * h;
      float rv = __shfl(linv, rl, 64);  // l for q-row rl
      int t = qw + rl;
      size_t p0 = (size_t)(b * TSEQ + t) * CDIM + hd * DH + lrow;
      O[p0] = f2bu(o0[r] * rv);
      O[p0 + 32] = f2bu(o1[r] * rv);
    }
  } else {
    int pidx = (bh << 4) + (qt - 16);
    uint16_t* Pb = Pbuf + ((size_t)pidx * 2 + chunk) * 8192;
    float* Pl = Plsum + ((size_t)pidx * 2 + chunk) * 128;
    #pragma unroll
    for (int r = 0; r < 16; ++r) {
      int rl = (r & 3) + 8 * (r >> 2) + 4 * h;
      int ql = 32 * w + rl;
      Pb[ql * 64 + lrow] = f2bu(o0[r]);
      Pb[ql * 64 + 32 + lrow] = f2bu(o1[r]);
    }
    if (h == 0) Pl[32 * w + lrow] = lsum;
  }
}

// ---------------- combine chunk partials: out = (o0+o1)/(l0+l1), write O ----------------
__global__ __launch_bounds__(256) void attn_reduce(
    const uint16_t* __restrict__ Pbuf, const float* __restrict__ Plsum,
    uint16_t* __restrict__ O) {
  int pidx = blockIdx.x;               // 0..383 = bh*16 + (qt-16)
  int bh = pidx >> 4, qrel = pidx & 15;
  int qt = 16 + qrel;
  int b = bh / NH, hd = bh - b * NH;
  int d = threadIdx.x & 63, qo = threadIdx.x >> 6;
  const uint16_t* p0 = Pbuf + (size_t)pidx * 2 * 8192;
  const uint16_t* p1 = p0 + 8192;
  const float* l0 = Plsum + (size_t)pidx * 2 * 128;
  const float* l1 = l0 + 128;
  #pragma unroll 4
  for (int q = qo; q < 128; q += 4) {
    float li = 1.0f / (l0[q] + l1[q]);
    float s = bu2f(p0[q * 64 + d]) + bu2f(p1[q * 64 + d]);
    int t = qt * 128 + q;
    O[(size_t)(b * TSEQ + t) * CDIM + hd * DH + d] = f2bu(s * li);
  }
}

extern "C" void kernel_launch(void* const* d_in, const int* in_sizes, int n_in,
                              void* d_out, int out_size, void* d_ws, size_t ws_size,
                              hipStream_t stream) {
  const float* x    = (const float*)d_in[0];
  const float* Wqkv = (const float*)d_in[1];
  const float* bqkv = (const float*)d_in[2];
  const float* Wout = (const float*)d_in[3];
  const float* bout = (const float*)d_in[4];
  float* out = (float*)d_out;
  char* ws = (char*)d_ws;

  uint16_t* Xb    = (uint16_t*)(ws + 0);          // 8192*768*2   = 12,582,912
  uint16_t* Wqkvt = (uint16_t*)(ws + 12582912);   // 2304*768*2   =  3,538,944
  uint16_t* Woutt = (uint16_t*)(ws + 16121856);   // 768*768*2    =  1,179,648
  uint16_t* Qb    = (uint16_t*)(ws + 17301504);   // 12,582,912 (pre-scaled)
  uint16_t* Kb    = (uint16_t*)(ws + 29884416);   // 12,582,912
  uint16_t* Vtb   = (uint16_t*)(ws + 42467328);   // 12,582,912 (V^T [B,H,Dh,T])
  uint16_t* Ob    = (uint16_t*)(ws + 55050240);   // 12,582,912 (end 67,633,152)
  // dead after gemm<0>: reuse as split-KV partial buffers (no extra ws)
  uint16_t* Pbuf  = Xb;                           // [384][2][128][64] bf16 = 12,582,912
  float*    Plsum = (float*)Wqkvt;                // [384][2][128] f32 = 393,216

  cast_f32_bf16<<<2048, 256, 0, stream>>>(x, Xb, (MROWS * CDIM) / 4);
  transpose_cast<<<dim3(24, 72), 256, 0, stream>>>(Wqkv, Wqkvt, 768, 2304);
  transpose_cast<<<dim3(24, 24), 256, 0, stream>>>(Wout, Woutt, 768, 768);
  gemm_bt<0><<<dim3(64, 18), 256, 0, stream>>>(Xb, Wqkvt, bqkv, Qb, Kb, Vtb, nullptr, 2304, 768);
  attn_part<<<1152, 256, 0, stream>>>(Qb, Kb, Vtb, Ob, Pbuf, Plsum);
  attn_reduce<<<384, 256, 0, stream>>>(Pbuf, Plsum, Ob);
  gemm_bt<1><<<dim3(64, 6), 256, 0, stream>>>(Ob, Woutt, bout, nullptr, nullptr, nullptr, out, 768, 768);
}

// Round 12
// 194.875 us; speedup vs baseline: 1.1634x; 1.1634x over previous
//
#include <hip/hip_runtime.h>
#include <hip/hip_bf16.h>
#include <cstdint>

#define NH 12
#define DH 64
#define TSEQ 4096
#define BATCH 2
#define CDIM 768
#define MROWS (BATCH*TSEQ)

typedef __bf16 bf16x8 __attribute__((ext_vector_type(8)));
typedef __bf16 bf16x4 __attribute__((ext_vector_type(4)));
typedef bf16x8 bf16x8_a __attribute__((may_alias));
typedef bf16x4 bf16x4_a __attribute__((may_alias));
typedef float f32x4 __attribute__((ext_vector_type(4)));

__device__ __forceinline__ uint16_t f2bu(float f) {
  uint32_t u = __float_as_uint(f);
  u += 0x7fffu + ((u >> 16) & 1u);
  return (uint16_t)(u >> 16);
}

__device__ __forceinline__ float bu2f(uint16_t x) {
  return __uint_as_float(((uint32_t)x) << 16);
}

__device__ __forceinline__ void gload_lds16(const void* g, void* l) {
  __builtin_amdgcn_global_load_lds(
      (const __attribute__((address_space(1))) void*)g,
      (__attribute__((address_space(3))) void*)l, 16, 0, 0);
}

// ---------------- cast fp32 -> bf16 (vectorized) ----------------
__global__ void cast_f32_bf16(const float* __restrict__ in, uint16_t* __restrict__ out, int n4) {
  int i = blockIdx.x * blockDim.x + threadIdx.x;
  int stride = gridDim.x * blockDim.x;
  for (; i < n4; i += stride) {
    float4 v = ((const float4*)in)[i];
    ushort4 o;
    o.x = f2bu(v.x); o.y = f2bu(v.y); o.z = f2bu(v.z); o.w = f2bu(v.w);
    ((ushort4*)out)[i] = o;
  }
}

// ---------------- transpose + cast: W[K][N] f32 -> Wt[N][K] bf16 ----------------
__global__ void transpose_cast(const float* __restrict__ w, uint16_t* __restrict__ wt, int K, int N) {
  __shared__ float tile[32][33];
  int kb = blockIdx.x * 32, nb = blockIdx.y * 32;
  int tx = threadIdx.x & 31, ty = threadIdx.x >> 5;
  #pragma unroll
  for (int r = ty; r < 32; r += 8) tile[r][tx] = w[(size_t)(kb + r) * N + nb + tx];
  __syncthreads();
  #pragma unroll
  for (int r = ty; r < 32; r += 8) wt[(size_t)(nb + r) * K + kb + tx] = f2bu(tile[tx][r]);
}

// ---------------- GEMM: C[M,N] = A[M,K](bf16) @ Bt[N,K]^T(bf16) + bias ----------------
template <int MODE>
__global__ __launch_bounds__(256) void gemm_bt(
    const uint16_t* __restrict__ A, const uint16_t* __restrict__ Bt,
    const float* __restrict__ bias,
    uint16_t* __restrict__ q, uint16_t* __restrict__ k, uint16_t* __restrict__ v,
    float* __restrict__ outf, int N, int K) {
  __shared__ uint16_t As[128 * 32];
  __shared__ uint16_t Bs[128 * 32];
  int tid = threadIdx.x;
  int w = tid >> 6, l = tid & 63;
  int lg = l >> 4, lr = l & 15;
  int mb = blockIdx.x * 128, nb = blockIdx.y * 128;
  int wr = (w >> 1) * 64, wc = (w & 1) * 64;
  f32x4 acc[4][4] = {};
  int srow = tid >> 2, scol = (tid & 3) * 8;
  const uint16_t* Ag = A + (size_t)(mb + srow) * K + scol;
  const uint16_t* Bg = Bt + (size_t)(nb + srow) * K + scol;
  char* AsB = (char*)As + (size_t)w * 1024;
  char* BsB = (char*)Bs + (size_t)w * 1024;
  size_t rowskip = (size_t)64 * K;
  for (int kb = 0; kb < K; kb += 32) {
    __syncthreads();
    gload_lds16(Ag + kb, AsB);
    gload_lds16(Ag + kb + rowskip, AsB + 4096);
    gload_lds16(Bg + kb, BsB);
    gload_lds16(Bg + kb + rowskip, BsB + 4096);
    __syncthreads();
    bf16x8 af[4], bfr[4];
    #pragma unroll
    for (int i = 0; i < 4; ++i)
      af[i] = *(const bf16x8_a*)(const void*)(As + (wr + i * 16 + lr) * 32 + lg * 8);
    #pragma unroll
    for (int i = 0; i < 4; ++i)
      bfr[i] = *(const bf16x8_a*)(const void*)(Bs + (wc + i * 16 + lr) * 32 + lg * 8);
    #pragma unroll
    for (int mi = 0; mi < 4; ++mi)
      #pragma unroll
      for (int ni = 0; ni < 4; ++ni)
        acc[mi][ni] = __builtin_amdgcn_mfma_f32_16x16x32_bf16(af[mi], bfr[ni], acc[mi][ni], 0, 0, 0);
  }
  #pragma unroll
  for (int mi = 0; mi < 4; ++mi) {
    #pragma unroll
    for (int ni = 0; ni < 4; ++ni) {
      if (MODE == 0) {
        int gm0 = mb + wr + mi * 16 + lg * 4;
        int gn = nb + wc + ni * 16 + lr;
        int which = gn / CDIM;
        int cc = gn - which * CDIM;
        int hh = cc >> 6, d = cc & 63;
        float bs = bias[gn];
        if (which == 2) {
          int b0 = gm0 >> 12, t0 = gm0 & 4095;
          ushort4 pk;
          pk.x = f2bu(acc[mi][ni][0] + bs);
          pk.y = f2bu(acc[mi][ni][1] + bs);
          pk.z = f2bu(acc[mi][ni][2] + bs);
          pk.w = f2bu(acc[mi][ni][3] + bs);
          *(ushort4*)&v[(((size_t)(b0 * NH + hh)) * DH + d) * TSEQ + t0] = pk;
        } else {
          uint16_t* dst = which ? k : q;
          float sc = which ? 1.0f : 0.1803368801111204f;  // 0.125 * log2(e)
          #pragma unroll
          for (int j = 0; j < 4; ++j) {
            int gm = gm0 + j;
            int bb = gm >> 12, t = gm & 4095;
            float val = (acc[mi][ni][j] + bs) * sc;
            dst[(((size_t)(bb * NH + hh)) * TSEQ + t) * DH + d] = f2bu(val);
          }
        }
      } else {
        #pragma unroll
        for (int j = 0; j < 4; ++j) {
          int gm = mb + wr + mi * 16 + lg * 4 + j;
          int gn = nb + wc + ni * 16 + lr;
          outf[(size_t)gm * N + gn] = acc[mi][ni][j] + bias[gn];
        }
      }
    }
  }
}

// ---------------- flash attention: 16x16 datapath, merged A/B substeps, dbuf, split-KV ----
// 256 thr / 4 waves; QBLK=128: wave w handles q-subs A at qb+16w and B at qb+64+16w.
// KVBLK=64, K/V double-buffered swizzled LDS (40KB total -> 4 blocks/CU), 1 barrier/tile:
// STAGE(t+1) issues into buf^1 before compute on buf (prefetch flies under compute).
// K/V fragments read ONCE per tile and fed to BOTH q-substeps (halves ds_read traffic).
// Fixed-reference softmax: p = exp2(S) directly (Q pre-scaled by 0.125*log2e);
// partials over disjoint k-ranges exactly additive -> split-KV without rescale.
// Swapped QK^T: S = mfma(K_frag, Q_frag); lane (lg,lr) holds S[q=lr][k=16ni+4lg+j].
// P through per-wave swizzled LDS tile (serial A-then-B reuse; wave-private, lgkm-ordered).
// gid = widx*24 + bh; widx<32: chunk blocks of qt=31..16; widx>=32: direct qt=15..0.
__global__ __launch_bounds__(256) void attn_part(
    const uint16_t* __restrict__ Q, const uint16_t* __restrict__ K,
    const uint16_t* __restrict__ Vt, uint16_t* __restrict__ O,
    uint16_t* __restrict__ Pbuf, float* __restrict__ Plsum) {
  int gid = blockIdx.x;
  int widx = gid / 24, bh = gid - widx * 24;
  int qt, t0, t1, chunk;
  bool direct;
  if (widx < 32) {
    qt = 31 - (widx >> 1); chunk = widx & 1; direct = false;
    t0 = chunk ? (qt + 1) : 0;
    t1 = chunk ? (2 * qt + 1) : qt;
  } else {
    qt = 47 - widx; chunk = 0; direct = true;
    t0 = 0; t1 = 2 * qt + 1;
  }
  int b = bh / NH, hd = bh - b * NH;
  size_t base = (size_t)bh * TSEQ * DH;
  int tid = threadIdx.x, w = tid >> 6, lane = tid & 63;
  int lg = lane >> 4, lr = lane & 15;
  __shared__ __align__(16) uint16_t Ks[2][64 * 64];
  __shared__ __align__(16) uint16_t Vs[2][64 * 64];
  __shared__ uint16_t Ps[4][16 * 64];
  char* pw = (char*)Ps[w];
  // staging: pre-swizzled global source, linear LDS dest (16B chunk c of row r at slot c^(r&7))
  int srow = tid >> 3;
  int schunk = (tid & 7) ^ (srow & 7);
  const uint16_t* Kg0 = K + base + (size_t)srow * DH + schunk * 8;
  const uint16_t* Vg0 = Vt + base + (size_t)srow * TSEQ + schunk * 8;
  int swzA = (lg ^ (lr & 7)) << 4;
  int swzB = swzA ^ 64;

  int qb = qt * 128;
  int qgA = qb + w * 16 + lr;           // lane's q row, sub A
  int qgB = qgA + 64;                   // sub B
  bf16x8 qA0 = *(const bf16x8_a*)(const void*)(Q + base + (size_t)qgA * DH + lg * 8);
  bf16x8 qA1 = *(const bf16x8_a*)(const void*)(Q + base + (size_t)qgA * DH + 32 + lg * 8);
  bf16x8 qB0 = *(const bf16x8_a*)(const void*)(Q + base + (size_t)qgB * DH + lg * 8);
  bf16x8 qB1 = *(const bf16x8_a*)(const void*)(Q + base + (size_t)qgB * DH + 32 + lg * 8);
  f32x4 oA[4] = {}, oB[4] = {};
  float lA = 0.f, lB = 0.f;
  int lg4 = lg * 4;
  int pofs = (lg & 1) * 8;

#define STAGE(bufi, tv) do { \
    char* kd_ = (char*)Ks[bufi] + w * 1024; \
    char* vd_ = (char*)Vs[bufi] + w * 1024; \
    const uint16_t* kg_ = Kg0 + (size_t)(tv) * (64 * DH); \
    const uint16_t* vg_ = Vg0 + (size_t)(tv) * 64; \
    gload_lds16(kg_,           kd_); \
    gload_lds16(kg_ + 32 * DH, kd_ + 4096); \
    gload_lds16(vg_,                     vd_); \
    gload_lds16(vg_ + (size_t)32 * TSEQ, vd_ + 4096); \
  } while (0)

  STAGE(0, t0);
  __syncthreads();                      // drain stage t0
  int cur = 0;
  for (int t = t0; t <= t1; ++t) {
    if (t + 1 <= t1) STAGE(cur ^ 1, t + 1);   // prefetch flies under this tile's compute
    const uint16_t* Kc = Ks[cur];
    const uint16_t* Vc = Vs[cur];
    bool doA = (t <= 2 * qt);           // wave-uniform (chunk1 blocks: A ends 1 tile early)
    int kb0 = t * 64;
    // ---- QK^T merged: each K-frag pair feeds both substeps ----
    f32x4 sA[4], sB[4];
    __builtin_amdgcn_s_setprio(1);
    #pragma unroll
    for (int ni = 0; ni < 4; ++ni) {
      const char* kbp = (const char*)Kc + (ni * 16 + lr) * 128;
      bf16x8 kf0 = *(const bf16x8_a*)(kbp + swzA);
      bf16x8 kf1 = *(const bf16x8_a*)(kbp + swzB);
      f32x4 s = {};
      s = __builtin_amdgcn_mfma_f32_16x16x32_bf16(kf0, qB0, s, 0, 0, 0);
      s = __builtin_amdgcn_mfma_f32_16x16x32_bf16(kf1, qB1, s, 0, 0, 0);
      sB[ni] = s;
      if (doA) {
        f32x4 sa = {};
        sa = __builtin_amdgcn_mfma_f32_16x16x32_bf16(kf0, qA0, sa, 0, 0, 0);
        sa = __builtin_amdgcn_mfma_f32_16x16x32_bf16(kf1, qA1, sa, 0, 0, 0);
        sA[ni] = sa;
      }
    }
    __builtin_amdgcn_s_setprio(0);
    // ---- substep A: mask + exp2 + P roundtrip ----
    bf16x8 pfA0, pfA1;
    if (doA) {
      if (t == 2 * qt) {
        int thr = qgA - kb0 - lg4;      // keep 16ni+j <= thr
        #pragma unroll
        for (int ni = 0; ni < 4; ++ni)
          #pragma unroll
          for (int j = 0; j < 4; ++j)
            sA[ni][j] = (16 * ni + j <= thr) ? sA[ni][j] : -1e30f;
      }
      #pragma unroll
      for (int ni = 0; ni < 4; ++ni) {
        float p0 = __builtin_amdgcn_exp2f(sA[ni][0]);
        float p1 = __builtin_amdgcn_exp2f(sA[ni][1]);
        float p2 = __builtin_amdgcn_exp2f(sA[ni][2]);
        float p3 = __builtin_amdgcn_exp2f(sA[ni][3]);
        lA += (p0 + p1) + (p2 + p3);
        bf16x4 pk;
        pk[0] = (__bf16)p0; pk[1] = (__bf16)p1; pk[2] = (__bf16)p2; pk[3] = (__bf16)p3;
        int chunkc = (2 * ni + (lg >> 1)) ^ (lr & 7);
        *(bf16x4_a*)(pw + lr * 128 + chunkc * 16 + pofs) = pk;
      }
      pfA0 = *(const bf16x8_a*)(pw + lr * 128 + swzA);
      pfA1 = *(const bf16x8_a*)(pw + lr * 128 + swzB);
    }
    // ---- substep B: mask + exp2 + P roundtrip (same pw region, after A reads retire) ----
    {
      if (t == 2 * qt + 1) {
        int thr = qgB - kb0 - lg4;
        #pragma unroll
        for (int ni = 0; ni < 4; ++ni)
          #pragma unroll
          for (int j = 0; j < 4; ++j)
            sB[ni][j] = (16 * ni + j <= thr) ? sB[ni][j] : -1e30f;
      }
      #pragma unroll
      for (int ni = 0; ni < 4; ++ni) {
        float p0 = __builtin_amdgcn_exp2f(sB[ni][0]);
        float p1 = __builtin_amdgcn_exp2f(sB[ni][1]);
        float p2 = __builtin_amdgcn_exp2f(sB[ni][2]);
        float p3 = __builtin_amdgcn_exp2f(sB[ni][3]);
        lB += (p0 + p1) + (p2 + p3);
        bf16x4 pk;
        pk[0] = (__bf16)p0; pk[1] = (__bf16)p1; pk[2] = (__bf16)p2; pk[3] = (__bf16)p3;
        int chunkc = (2 * ni + (lg >> 1)) ^ (lr & 7);
        *(bf16x4_a*)(pw + lr * 128 + chunkc * 16 + pofs) = pk;
      }
    }
    bf16x8 pfB0 = *(const bf16x8_a*)(pw + lr * 128 + swzA);
    bf16x8 pfB1 = *(const bf16x8_a*)(pw + lr * 128 + swzB);
    // ---- PV merged: each V-frag pair feeds both substeps ----
    __builtin_amdgcn_s_setprio(1);
    #pragma unroll
    for (int nd = 0; nd < 4; ++nd) {
      const char* vb = (const char*)Vc + (nd * 16 + lr) * 128;
      bf16x8 vf0 = *(const bf16x8_a*)(vb + swzA);
      bf16x8 vf1 = *(const bf16x8_a*)(vb + swzB);
      oB[nd] = __builtin_amdgcn_mfma_f32_16x16x32_bf16(pfB0, vf0, oB[nd], 0, 0, 0);
      oB[nd] = __builtin_amdgcn_mfma_f32_16x16x32_bf16(pfB1, vf1, oB[nd], 0, 0, 0);
      if (doA) {
        oA[nd] = __builtin_amdgcn_mfma_f32_16x16x32_bf16(pfA0, vf0, oA[nd], 0, 0, 0);
        oA[nd] = __builtin_amdgcn_mfma_f32_16x16x32_bf16(pfA1, vf1, oA[nd], 0, 0, 0);
      }
    }
    __builtin_amdgcn_s_setprio(0);
    __syncthreads();                    // drains prefetch; all waves done with buf[cur]
    cur ^= 1;
  }
#undef STAGE

  lA += __shfl_xor(lA, 16, 64); lA += __shfl_xor(lA, 32, 64);
  lB += __shfl_xor(lB, 16, 64); lB += __shfl_xor(lB, 32, 64);
  if (direct) {
    float riA = 1.0f / lA, riB = 1.0f / lB;
    #pragma unroll
    for (int j = 0; j < 4; ++j) {
      float rvA = __shfl(riA, (lane & 48) | (lg4 + j), 64);
      float rvB = __shfl(riB, (lane & 48) | (lg4 + j), 64);
      int tA = qb + w * 16 + lg4 + j;
      size_t pA = (size_t)(b * TSEQ + tA) * CDIM + hd * DH + lr;
      size_t pB = pA + (size_t)64 * CDIM;
      #pragma unroll
      for (int nd = 0; nd < 4; ++nd) {
        O[pA + nd * 16] = f2bu(oA[nd][j] * rvA);
        O[pB + nd * 16] = f2bu(oB[nd][j] * rvB);
      }
    }
  } else {
    int pidx = (bh << 4) + (qt - 16);
    uint16_t* Pb = Pbuf + ((size_t)pidx * 2 + chunk) * 8192;
    float* Pl = Plsum + ((size_t)pidx * 2 + chunk) * 128;
    #pragma unroll
    for (int j = 0; j < 4; ++j) {
      int qlA = w * 16 + lg4 + j;
      #pragma unroll
      for (int nd = 0; nd < 4; ++nd) {
        Pb[qlA * 64 + nd * 16 + lr] = f2bu(oA[nd][j]);
        Pb[(64 + qlA) * 64 + nd * 16 + lr] = f2bu(oB[nd][j]);
      }
    }
    if (lane < 16) {                    // lg==0 lanes hold l for q-row lr
      Pl[w * 16 + lane] = lA;
      Pl[64 + w * 16 + lane] = lB;
    }
  }
}

// ---------------- combine chunk partials: out = (o0+o1)/(l0+l1), write O ----------------
__global__ __launch_bounds__(256) void attn_reduce(
    const uint16_t* __restrict__ Pbuf, const float* __restrict__ Plsum,
    uint16_t* __restrict__ O) {
  int pidx = blockIdx.x;               // 0..383 = bh*16 + (qt-16)
  int bh = pidx >> 4, qrel = pidx & 15;
  int qt = 16 + qrel;
  int b = bh / NH, hd = bh - b * NH;
  int d = threadIdx.x & 63, qo = threadIdx.x >> 6;
  const uint16_t* p0 = Pbuf + (size_t)pidx * 2 * 8192;
  const uint16_t* p1 = p0 + 8192;
  const float* l0 = Plsum + (size_t)pidx * 2 * 128;
  const float* l1 = l0 + 128;
  #pragma unroll 4
  for (int q = qo; q < 128; q += 4) {
    float li = 1.0f / (l0[q] + l1[q]);
    float s = bu2f(p0[q * 64 + d]) + bu2f(p1[q * 64 + d]);
    int t = qt * 128 + q;
    O[(size_t)(b * TSEQ + t) * CDIM + hd * DH + d] = f2bu(s * li);
  }
}

extern "C" void kernel_launch(void* const* d_in, const int* in_sizes, int n_in,
                              void* d_out, int out_size, void* d_ws, size_t ws_size,
                              hipStream_t stream) {
  const float* x    = (const float*)d_in[0];
  const float* Wqkv = (const float*)d_in[1];
  const float* bqkv = (const float*)d_in[2];
  const float* Wout = (const float*)d_in[3];
  const float* bout = (const float*)d_in[4];
  float* out = (float*)d_out;
  char* ws = (char*)d_ws;

  uint16_t* Xb    = (uint16_t*)(ws + 0);          // 8192*768*2   = 12,582,912
  uint16_t* Wqkvt = (uint16_t*)(ws + 12582912);   // 2304*768*2   =  3,538,944
  uint16_t* Woutt = (uint16_t*)(ws + 16121856);   // 768*768*2    =  1,179,648
  uint16_t* Qb    = (uint16_t*)(ws + 17301504);   // 12,582,912 (pre-scaled)
  uint16_t* Kb    = (uint16_t*)(ws + 29884416);   // 12,582,912
  uint16_t* Vtb   = (uint16_t*)(ws + 42467328);   // 12,582,912 (V^T [B,H,Dh,T])
  uint16_t* Ob    = (uint16_t*)(ws + 55050240);   // 12,582,912 (end 67,633,152)
  // dead after gemm<0>: reuse as split-KV partial buffers (no extra ws)
  uint16_t* Pbuf  = Xb;                           // [384][2][128][64] bf16 = 12,582,912
  float*    Plsum = (float*)Wqkvt;                // [384][2][128] f32 = 393,216

  cast_f32_bf16<<<2048, 256, 0, stream>>>(x, Xb, (MROWS * CDIM) / 4);
  transpose_cast<<<dim3(24, 72), 256, 0, stream>>>(Wqkv, Wqkvt, 768, 2304);
  transpose_cast<<<dim3(24, 24), 256, 0, stream>>>(Wout, Woutt, 768, 768);
  gemm_bt<0><<<dim3(64, 18), 256, 0, stream>>>(Xb, Wqkvt, bqkv, Qb, Kb, Vtb, nullptr, 2304, 768);
  attn_part<<<1152, 256, 0, stream>>>(Qb, Kb, Vtb, Ob, Pbuf, Plsum);
  attn_reduce<<<384, 256, 0, stream>>>(Pbuf, Plsum, Ob);
  gemm_bt<1><<<dim3(64, 6), 256, 0, stream>>>(Ob, Woutt, bout, nullptr, nullptr, nullptr, out, 768, 768);
}

// Round 13
// 191.475 us; speedup vs baseline: 1.1841x; 1.0178x over previous
//
#include <hip/hip_runtime.h>
#include <hip/hip_bf16.h>
#include <cstdint>

#define NH 12
#define DH 64
#define TSEQ 4096
#define BATCH 2
#define CDIM 768
#define MROWS (BATCH*TSEQ)

typedef __bf16 bf16x8 __attribute__((ext_vector_type(8)));
typedef __bf16 bf16x4 __attribute__((ext_vector_type(4)));
typedef bf16x8 bf16x8_a __attribute__((may_alias));
typedef bf16x4 bf16x4_a __attribute__((may_alias));
typedef float f32x4 __attribute__((ext_vector_type(4)));

__device__ __forceinline__ uint16_t f2bu(float f) {
  uint32_t u = __float_as_uint(f);
  u += 0x7fffu + ((u >> 16) & 1u);
  return (uint16_t)(u >> 16);
}

__device__ __forceinline__ float bu2f(uint16_t x) {
  return __uint_as_float(((uint32_t)x) << 16);
}

__device__ __forceinline__ void gload_lds16(const void* g, void* l) {
  __builtin_amdgcn_global_load_lds(
      (const __attribute__((address_space(1))) void*)g,
      (__attribute__((address_space(3))) void*)l, 16, 0, 0);
}

// ---------------- cast fp32 -> bf16 (vectorized) ----------------
__global__ void cast_f32_bf16(const float* __restrict__ in, uint16_t* __restrict__ out, int n4) {
  int i = blockIdx.x * blockDim.x + threadIdx.x;
  int stride = gridDim.x * blockDim.x;
  for (; i < n4; i += stride) {
    float4 v = ((const float4*)in)[i];
    ushort4 o;
    o.x = f2bu(v.x); o.y = f2bu(v.y); o.z = f2bu(v.z); o.w = f2bu(v.w);
    ((ushort4*)out)[i] = o;
  }
}

// ---------------- transpose + cast: W[K][N] f32 -> Wt[N][K] bf16 ----------------
__global__ void transpose_cast(const float* __restrict__ w, uint16_t* __restrict__ wt, int K, int N) {
  __shared__ float tile[32][33];
  int kb = blockIdx.x * 32, nb = blockIdx.y * 32;
  int tx = threadIdx.x & 31, ty = threadIdx.x >> 5;
  #pragma unroll
  for (int r = ty; r < 32; r += 8) tile[r][tx] = w[(size_t)(kb + r) * N + nb + tx];
  __syncthreads();
  #pragma unroll
  for (int r = ty; r < 32; r += 8) wt[(size_t)(nb + r) * K + kb + tx] = f2bu(tile[tx][r]);
}

// ---------------- QKV GEMM: scatter Q(pre-scaled)/K -> [B,H,T,Dh], V -> V^T [B,H,Dh,T] ----
__global__ __launch_bounds__(256) void gemm_qkv(
    const uint16_t* __restrict__ A, const uint16_t* __restrict__ Bt,
    const float* __restrict__ bias,
    uint16_t* __restrict__ q, uint16_t* __restrict__ k, uint16_t* __restrict__ v,
    int N, int K) {
  __shared__ uint16_t As[128 * 32];
  __shared__ uint16_t Bs[128 * 32];
  int tid = threadIdx.x;
  int w = tid >> 6, l = tid & 63;
  int lg = l >> 4, lr = l & 15;
  int mb = blockIdx.x * 128, nb = blockIdx.y * 128;
  int wr = (w >> 1) * 64, wc = (w & 1) * 64;
  f32x4 acc[4][4] = {};
  int srow = tid >> 2, scol = (tid & 3) * 8;
  const uint16_t* Ag = A + (size_t)(mb + srow) * K + scol;
  const uint16_t* Bg = Bt + (size_t)(nb + srow) * K + scol;
  char* AsB = (char*)As + (size_t)w * 1024;
  char* BsB = (char*)Bs + (size_t)w * 1024;
  size_t rowskip = (size_t)64 * K;
  for (int kb = 0; kb < K; kb += 32) {
    __syncthreads();
    gload_lds16(Ag + kb, AsB);
    gload_lds16(Ag + kb + rowskip, AsB + 4096);
    gload_lds16(Bg + kb, BsB);
    gload_lds16(Bg + kb + rowskip, BsB + 4096);
    __syncthreads();
    bf16x8 af[4], bfr[4];
    #pragma unroll
    for (int i = 0; i < 4; ++i)
      af[i] = *(const bf16x8_a*)(const void*)(As + (wr + i * 16 + lr) * 32 + lg * 8);
    #pragma unroll
    for (int i = 0; i < 4; ++i)
      bfr[i] = *(const bf16x8_a*)(const void*)(Bs + (wc + i * 16 + lr) * 32 + lg * 8);
    #pragma unroll
    for (int mi = 0; mi < 4; ++mi)
      #pragma unroll
      for (int ni = 0; ni < 4; ++ni)
        acc[mi][ni] = __builtin_amdgcn_mfma_f32_16x16x32_bf16(af[mi], bfr[ni], acc[mi][ni], 0, 0, 0);
  }
  #pragma unroll
  for (int mi = 0; mi < 4; ++mi) {
    #pragma unroll
    for (int ni = 0; ni < 4; ++ni) {
      int gm0 = mb + wr + mi * 16 + lg * 4;
      int gn = nb + wc + ni * 16 + lr;
      int which = gn / CDIM;
      int cc = gn - which * CDIM;
      int hh = cc >> 6, d = cc & 63;
      float bs = bias[gn];
      if (which == 2) {
        int b0 = gm0 >> 12, t0 = gm0 & 4095;
        ushort4 pk;
        pk.x = f2bu(acc[mi][ni][0] + bs);
        pk.y = f2bu(acc[mi][ni][1] + bs);
        pk.z = f2bu(acc[mi][ni][2] + bs);
        pk.w = f2bu(acc[mi][ni][3] + bs);
        *(ushort4*)&v[(((size_t)(b0 * NH + hh)) * DH + d) * TSEQ + t0] = pk;
      } else {
        uint16_t* dst = which ? k : q;
        float sc = which ? 1.0f : 0.1803368801111204f;  // 0.125 * log2(e)
        #pragma unroll
        for (int j = 0; j < 4; ++j) {
          int gm = gm0 + j;
          int bb = gm >> 12, t = gm & 4095;
          float val = (acc[mi][ni][j] + bs) * sc;
          dst[(((size_t)(bb * NH + hh)) * TSEQ + t) * DH + d] = f2bu(val);
        }
      }
    }
  }
}

// ---------------- out-proj GEMM: BM=128, BN=64 -> grid 64x12 = 768 blocks (occupancy) ----
// wave w owns rows wr=32w..+31 x all 64 cols; acc[2][4] 16x16 frags.
__global__ __launch_bounds__(256) void gemm_out(
    const uint16_t* __restrict__ A, const uint16_t* __restrict__ Bt,
    const float* __restrict__ bias, float* __restrict__ outf, int N, int K) {
  __shared__ uint16_t As[128 * 32];
  __shared__ uint16_t Bs[64 * 32];
  int tid = threadIdx.x;
  int w = tid >> 6, l = tid & 63;
  int lg = l >> 4, lr = l & 15;
  int mb = blockIdx.x * 128, nb = blockIdx.y * 64;
  int wr = w * 32;
  f32x4 acc[2][4] = {};
  int srow = tid >> 2, scol = (tid & 3) * 8;
  const uint16_t* Ag = A + (size_t)(mb + srow) * K + scol;
  const uint16_t* Bg = Bt + (size_t)(nb + srow) * K + scol;   // srow 0..63 used for B
  char* AsB = (char*)As + (size_t)w * 1024;
  char* BsB = (char*)Bs + (size_t)w * 1024;
  size_t rowskip = (size_t)64 * K;
  for (int kb = 0; kb < K; kb += 32) {
    __syncthreads();
    gload_lds16(Ag + kb, AsB);
    gload_lds16(Ag + kb + rowskip, AsB + 4096);
    gload_lds16(Bg + kb, BsB);                 // 64 rows x 32 cols = 4KB
    __syncthreads();
    bf16x8 af[2], bfr[4];
    #pragma unroll
    for (int i = 0; i < 2; ++i)
      af[i] = *(const bf16x8_a*)(const void*)(As + (wr + i * 16 + lr) * 32 + lg * 8);
    #pragma unroll
    for (int i = 0; i < 4; ++i)
      bfr[i] = *(const bf16x8_a*)(const void*)(Bs + (i * 16 + lr) * 32 + lg * 8);
    #pragma unroll
    for (int mi = 0; mi < 2; ++mi)
      #pragma unroll
      for (int ni = 0; ni < 4; ++ni)
        acc[mi][ni] = __builtin_amdgcn_mfma_f32_16x16x32_bf16(af[mi], bfr[ni], acc[mi][ni], 0, 0, 0);
  }
  #pragma unroll
  for (int mi = 0; mi < 2; ++mi) {
    #pragma unroll
    for (int ni = 0; ni < 4; ++ni) {
      #pragma unroll
      for (int j = 0; j < 4; ++j) {
        int gm = mb + wr + mi * 16 + lg * 4 + j;
        int gn = nb + ni * 16 + lr;
        outf[(size_t)gm * N + gn] = acc[mi][ni][j] + bias[gn];
      }
    }
  }
}

// ---------------- flash attention: merged A/B substeps, single-buffer 24KB, split-KV ----
// 256 thr / 4 waves; QBLK=128: wave w handles q-subs A at qb+16w and B at qb+64+16w.
// KVBLK=64, single-buffered swizzled LDS (24KB -> 6 blocks/CU), 2 barriers/tile (r9 skel).
// K/V fragments read ONCE per tile, feed BOTH q-substeps (r12 merged compute).
// Fixed-reference softmax: p = exp2(S) directly (Q pre-scaled by 0.125*log2e);
// partials over disjoint k-ranges exactly additive -> split-KV without rescale.
// Swapped QK^T: S = mfma(K_frag, Q_frag); lane (lg,lr) holds S[q=lr][k=16ni+4lg+j].
// P via per-wave swizzled LDS tile (serial A-then-B reuse; wave-private, in-order DS pipe).
// gid = widx*24 + bh; widx<32: chunk blocks of qt=31..16; widx>=32: direct qt=15..0.
__global__ __launch_bounds__(256) void attn_part(
    const uint16_t* __restrict__ Q, const uint16_t* __restrict__ K,
    const uint16_t* __restrict__ Vt, uint16_t* __restrict__ O,
    uint16_t* __restrict__ Pbuf, float* __restrict__ Plsum) {
  int gid = blockIdx.x;
  int widx = gid / 24, bh = gid - widx * 24;
  int qt, t0, t1, chunk;
  bool direct;
  if (widx < 32) {
    qt = 31 - (widx >> 1); chunk = widx & 1; direct = false;
    t0 = chunk ? (qt + 1) : 0;
    t1 = chunk ? (2 * qt + 1) : qt;
  } else {
    qt = 47 - widx; chunk = 0; direct = true;
    t0 = 0; t1 = 2 * qt + 1;
  }
  int b = bh / NH, hd = bh - b * NH;
  size_t base = (size_t)bh * TSEQ * DH;
  int tid = threadIdx.x, w = tid >> 6, lane = tid & 63;
  int lg = lane >> 4, lr = lane & 15;
  __shared__ __align__(16) uint16_t Ks[64 * 64];
  __shared__ __align__(16) uint16_t Vs[64 * 64];
  __shared__ uint16_t Ps[4][16 * 64];
  char* pw = (char*)Ps[w];
  // staging: pre-swizzled global source, linear LDS dest (16B chunk c of row r at slot c^(r&7))
  int srow = tid >> 3;
  int schunk = (tid & 7) ^ (srow & 7);
  const uint16_t* Kg0 = K + base + (size_t)srow * DH + schunk * 8;
  const uint16_t* Vg0 = Vt + base + (size_t)srow * TSEQ + schunk * 8;
  char* KsB = (char*)Ks + w * 1024;
  char* VsB = (char*)Vs + w * 1024;
  int swzA = (lg ^ (lr & 7)) << 4;
  int swzB = swzA ^ 64;

  int qb = qt * 128;
  int qgA = qb + w * 16 + lr;           // lane's q row, sub A
  int qgB = qgA + 64;                   // sub B
  bf16x8 qA0 = *(const bf16x8_a*)(const void*)(Q + base + (size_t)qgA * DH + lg * 8);
  bf16x8 qA1 = *(const bf16x8_a*)(const void*)(Q + base + (size_t)qgA * DH + 32 + lg * 8);
  bf16x8 qB0 = *(const bf16x8_a*)(const void*)(Q + base + (size_t)qgB * DH + lg * 8);
  bf16x8 qB1 = *(const bf16x8_a*)(const void*)(Q + base + (size_t)qgB * DH + 32 + lg * 8);
  f32x4 oA[4] = {}, oB[4] = {};
  float lA = 0.f, lB = 0.f;
  int lg4 = lg * 4;
  int pofs = (lg & 1) * 8;

  for (int t = t0; t <= t1; ++t) {
    __syncthreads();                    // all waves done reading previous tile
    {
      const uint16_t* kg_ = Kg0 + (size_t)t * (64 * DH);
      const uint16_t* vg_ = Vg0 + (size_t)t * 64;
      gload_lds16(kg_,           KsB);
      gload_lds16(kg_ + 32 * DH, KsB + 4096);
      gload_lds16(vg_,                     VsB);
      gload_lds16(vg_ + (size_t)32 * TSEQ, VsB + 4096);
    }
    __syncthreads();                    // stage complete (vmcnt drain)
    bool doA = (t <= 2 * qt);           // wave-uniform (chunk1 blocks: A ends 1 tile early)
    int kb0 = t * 64;
    // ---- QK^T merged: each K-frag pair feeds both substeps ----
    f32x4 sA[4], sB[4];
    __builtin_amdgcn_s_setprio(1);
    #pragma unroll
    for (int ni = 0; ni < 4; ++ni) {
      const char* kbp = (const char*)Ks + (ni * 16 + lr) * 128;
      bf16x8 kf0 = *(const bf16x8_a*)(kbp + swzA);
      bf16x8 kf1 = *(const bf16x8_a*)(kbp + swzB);
      f32x4 s = {};
      s = __builtin_amdgcn_mfma_f32_16x16x32_bf16(kf0, qB0, s, 0, 0, 0);
      s = __builtin_amdgcn_mfma_f32_16x16x32_bf16(kf1, qB1, s, 0, 0, 0);
      sB[ni] = s;
      if (doA) {
        f32x4 sa = {};
        sa = __builtin_amdgcn_mfma_f32_16x16x32_bf16(kf0, qA0, sa, 0, 0, 0);
        sa = __builtin_amdgcn_mfma_f32_16x16x32_bf16(kf1, qA1, sa, 0, 0, 0);
        sA[ni] = sa;
      }
    }
    __builtin_amdgcn_s_setprio(0);
    // ---- substep A: mask + exp2 + P roundtrip ----
    bf16x8 pfA0, pfA1;
    if (doA) {
      if (t == 2 * qt) {
        int thr = qgA - kb0 - lg4;      // keep 16ni+j <= thr
        #pragma unroll
        for (int ni = 0; ni < 4; ++ni)
          #pragma unroll
          for (int j = 0; j < 4; ++j)
            sA[ni][j] = (16 * ni + j <= thr) ? sA[ni][j] : -1e30f;
      }
      #pragma unroll
      for (int ni = 0; ni < 4; ++ni) {
        float p0 = __builtin_amdgcn_exp2f(sA[ni][0]);
        float p1 = __builtin_amdgcn_exp2f(sA[ni][1]);
        float p2 = __builtin_amdgcn_exp2f(sA[ni][2]);
        float p3 = __builtin_amdgcn_exp2f(sA[ni][3]);
        lA += (p0 + p1) + (p2 + p3);
        bf16x4 pk;
        pk[0] = (__bf16)p0; pk[1] = (__bf16)p1; pk[2] = (__bf16)p2; pk[3] = (__bf16)p3;
        int chunkc = (2 * ni + (lg >> 1)) ^ (lr & 7);
        *(bf16x4_a*)(pw + lr * 128 + chunkc * 16 + pofs) = pk;
      }
      pfA0 = *(const bf16x8_a*)(pw + lr * 128 + swzA);
      pfA1 = *(const bf16x8_a*)(pw + lr * 128 + swzB);
    }
    // ---- substep B: mask + exp2 + P roundtrip (same pw region, after A reads retire) ----
    {
      if (t == 2 * qt + 1) {
        int thr = qgB - kb0 - lg4;
        #pragma unroll
        for (int ni = 0; ni < 4; ++ni)
          #pragma unroll
          for (int j = 0; j < 4; ++j)
            sB[ni][j] = (16 * ni + j <= thr) ? sB[ni][j] : -1e30f;
      }
      #pragma unroll
      for (int ni = 0; ni < 4; ++ni) {
        float p0 = __builtin_amdgcn_exp2f(sB[ni][0]);
        float p1 = __builtin_amdgcn_exp2f(sB[ni][1]);
        float p2 = __builtin_amdgcn_exp2f(sB[ni][2]);
        float p3 = __builtin_amdgcn_exp2f(sB[ni][3]);
        lB += (p0 + p1) + (p2 + p3);
        bf16x4 pk;
        pk[0] = (__bf16)p0; pk[1] = (__bf16)p1; pk[2] = (__bf16)p2; pk[3] = (__bf16)p3;
        int chunkc = (2 * ni + (lg >> 1)) ^ (lr & 7);
        *(bf16x4_a*)(pw + lr * 128 + chunkc * 16 + pofs) = pk;
      }
    }
    bf16x8 pfB0 = *(const bf16x8_a*)(pw + lr * 128 + swzA);
    bf16x8 pfB1 = *(const bf16x8_a*)(pw + lr * 128 + swzB);
    // ---- PV merged: each V-frag pair feeds both substeps ----
    __builtin_amdgcn_s_setprio(1);
    #pragma unroll
    for (int nd = 0; nd < 4; ++nd) {
      const char* vb = (const char*)Vs + (nd * 16 + lr) * 128;
      bf16x8 vf0 = *(const bf16x8_a*)(vb + swzA);
      bf16x8 vf1 = *(const bf16x8_a*)(vb + swzB);
      oB[nd] = __builtin_amdgcn_mfma_f32_16x16x32_bf16(pfB0, vf0, oB[nd], 0, 0, 0);
      oB[nd] = __builtin_amdgcn_mfma_f32_16x16x32_bf16(pfB1, vf1, oB[nd], 0, 0, 0);
      if (doA) {
        oA[nd] = __builtin_amdgcn_mfma_f32_16x16x32_bf16(pfA0, vf0, oA[nd], 0, 0, 0);
        oA[nd] = __builtin_amdgcn_mfma_f32_16x16x32_bf16(pfA1, vf1, oA[nd], 0, 0, 0);
      }
    }
    __builtin_amdgcn_s_setprio(0);
  }

  lA += __shfl_xor(lA, 16, 64); lA += __shfl_xor(lA, 32, 64);
  lB += __shfl_xor(lB, 16, 64); lB += __shfl_xor(lB, 32, 64);
  if (direct) {
    float riA = 1.0f / lA, riB = 1.0f / lB;
    #pragma unroll
    for (int j = 0; j < 4; ++j) {
      float rvA = __shfl(riA, (lane & 48) | (lg4 + j), 64);
      float rvB = __shfl(riB, (lane & 48) | (lg4 + j), 64);
      int tA = qb + w * 16 + lg4 + j;
      size_t pA = (size_t)(b * TSEQ + tA) * CDIM + hd * DH + lr;
      size_t pB = pA + (size_t)64 * CDIM;
      #pragma unroll
      for (int nd = 0; nd < 4; ++nd) {
        O[pA + nd * 16] = f2bu(oA[nd][j] * rvA);
        O[pB + nd * 16] = f2bu(oB[nd][j] * rvB);
      }
    }
  } else {
    int pidx = (bh << 4) + (qt - 16);
    uint16_t* Pb = Pbuf + ((size_t)pidx * 2 + chunk) * 8192;
    float* Pl = Plsum + ((size_t)pidx * 2 + chunk) * 128;
    #pragma unroll
    for (int j = 0; j < 4; ++j) {
      int qlA = w * 16 + lg4 + j;
      #pragma unroll
      for (int nd = 0; nd < 4; ++nd) {
        Pb[qlA * 64 + nd * 16 + lr] = f2bu(oA[nd][j]);
        Pb[(64 + qlA) * 64 + nd * 16 + lr] = f2bu(oB[nd][j]);
      }
    }
    if (lane < 16) {                    // lg==0 lanes hold l for q-row lr
      Pl[w * 16 + lane] = lA;
      Pl[64 + w * 16 + lane] = lB;
    }
  }
}

// ---------------- combine chunk partials: out = (o0+o1)/(l0+l1), write O ----------------
__global__ __launch_bounds__(256) void attn_reduce(
    const uint16_t* __restrict__ Pbuf, const float* __restrict__ Plsum,
    uint16_t* __restrict__ O) {
  int pidx = blockIdx.x;               // 0..383 = bh*16 + (qt-16)
  int bh = pidx >> 4, qrel = pidx & 15;
  int qt = 16 + qrel;
  int b = bh / NH, hd = bh - b * NH;
  int d = threadIdx.x & 63, qo = threadIdx.x >> 6;
  const uint16_t* p0 = Pbuf + (size_t)pidx * 2 * 8192;
  const uint16_t* p1 = p0 + 8192;
  const float* l0 = Plsum + (size_t)pidx * 2 * 128;
  const float* l1 = l0 + 128;
  #pragma unroll 4
  for (int q = qo; q < 128; q += 4) {
    float li = 1.0f / (l0[q] + l1[q]);
    float s = bu2f(p0[q * 64 + d]) + bu2f(p1[q * 64 + d]);
    int t = qt * 128 + q;
    O[(size_t)(b * TSEQ + t) * CDIM + hd * DH + d] = f2bu(s * li);
  }
}

extern "C" void kernel_launch(void* const* d_in, const int* in_sizes, int n_in,
                              void* d_out, int out_size, void* d_ws, size_t ws_size,
                              hipStream_t stream) {
  const float* x    = (const float*)d_in[0];
  const float* Wqkv = (const float*)d_in[1];
  const float* bqkv = (const float*)d_in[2];
  const float* Wout = (const float*)d_in[3];
  const float* bout = (const float*)d_in[4];
  float* out = (float*)d_out;
  char* ws = (char*)d_ws;

  uint16_t* Xb    = (uint16_t*)(ws + 0);          // 8192*768*2   = 12,582,912
  uint16_t* Wqkvt = (uint16_t*)(ws + 12582912);   // 2304*768*2   =  3,538,944
  uint16_t* Woutt = (uint16_t*)(ws + 16121856);   // 768*768*2    =  1,179,648
  uint16_t* Qb    = (uint16_t*)(ws + 17301504);   // 12,582,912 (pre-scaled)
  uint16_t* Kb    = (uint16_t*)(ws + 29884416);   // 12,582,912
  uint16_t* Vtb   = (uint16_t*)(ws + 42467328);   // 12,582,912 (V^T [B,H,Dh,T])
  uint16_t* Ob    = (uint16_t*)(ws + 55050240);   // 12,582,912 (end 67,633,152)
  // dead after gemm_qkv: reuse as split-KV partial buffers (no extra ws)
  uint16_t* Pbuf  = Xb;                           // [384][2][128][64] bf16 = 12,582,912
  float*    Plsum = (float*)Wqkvt;                // [384][2][128] f32 = 393,216

  cast_f32_bf16<<<2048, 256, 0, stream>>>(x, Xb, (MROWS * CDIM) / 4);
  transpose_cast<<<dim3(24, 72), 256, 0, stream>>>(Wqkv, Wqkvt, 768, 2304);
  transpose_cast<<<dim3(24, 24), 256, 0, stream>>>(Wout, Woutt, 768, 768);
  gemm_qkv<<<dim3(64, 18), 256, 0, stream>>>(Xb, Wqkvt, bqkv, Qb, Kb, Vtb, 2304, 768);
  attn_part<<<1152, 256, 0, stream>>>(Qb, Kb, Vtb, Ob, Pbuf, Plsum);
  attn_reduce<<<384, 256, 0, stream>>>(Pbuf, Plsum, Ob);
  gemm_out<<<dim3(64, 12), 256, 0, stream>>>(Ob, Woutt, bout, out, 768, 768);
}